// Round 1
// baseline (445.212 us; speedup 1.0000x reference)
//
#include <hip/hip_runtime.h>
#include <hip/hip_bf16.h>
#include <math.h>

#define BB 64
#define QQ 900
#define GG 100
#define NCLS 10
#define CP1 11

#define CLS_W 2.0f
#define L1_W 5.0f
#define GIOU_W 2.0f

struct Accum {
  double wnll;   // sum w * nll
  double wt;     // sum w
  double l1;     // sum |dbox|
  double gl;     // sum (1 - giou)
  int nm;        // matched count
  int pad[7];
};

// ---------------- init ----------------
__global__ void init_kernel(Accum* acc) {
  if (threadIdx.x == 0) {
    acc->wnll = 0.0; acc->wt = 0.0; acc->l1 = 0.0; acc->gl = 0.0; acc->nm = 0;
  }
}

// ---------------- cost matrix: cost[b][g][q] (transposed layout for JV rows) ----------------
__global__ __launch_bounds__(256) void cost_kernel(
    const float* __restrict__ logits, const float* __restrict__ pboxes,
    const int* __restrict__ gcls, const float* __restrict__ gboxes,
    float* __restrict__ cost) {
  const int b = blockIdx.y;
  const int q = blockIdx.x * 256 + threadIdx.x;

  __shared__ float s_gb[GG * 4];
  __shared__ int   s_gc[GG];
  __shared__ float s_prob[256 * 13];   // stride 13: conflict-free for uniform class idx

  for (int i = threadIdx.x; i < GG * 4; i += 256) s_gb[i] = gboxes[b * GG * 4 + i];
  for (int i = threadIdx.x; i < GG; i += 256)     s_gc[i] = gcls[b * GG + i];

  float pcx = 0.f, pcy = 0.f, pw = 0.f, ph = 0.f;
  if (q < QQ) {
    const float* lg = logits + ((size_t)b * QQ + q) * CP1;
    float l[CP1];
    float mx = -1e30f;
    for (int c = 0; c < CP1; ++c) { l[c] = lg[c]; mx = fmaxf(mx, l[c]); }
    float se = 0.f;
    for (int c = 0; c < CP1; ++c) { l[c] = expf(l[c] - mx); se += l[c]; }
    float inv = 1.0f / se;
    for (int c = 0; c < CP1; ++c) s_prob[threadIdx.x * 13 + c] = l[c] * inv;
    const float* pb = pboxes + ((size_t)b * QQ + q) * 4;
    pcx = pb[0]; pcy = pb[1]; pw = pb[2]; ph = pb[3];
  }
  __syncthreads();
  if (q >= QQ) return;

  const float px1 = pcx - 0.5f * pw, py1 = pcy - 0.5f * ph;
  const float px2 = pcx + 0.5f * pw, py2 = pcy + 0.5f * ph;
  const float pa = fmaxf(px2 - px1, 0.f) * fmaxf(py2 - py1, 0.f);

  float* crow = cost + ((size_t)b * GG) * QQ + q;
  for (int g = 0; g < GG; ++g) {
    int cls = s_gc[g];
    cls = cls < 0 ? 0 : (cls > NCLS - 1 ? NCLS - 1 : cls);
    const float cc = -s_prob[threadIdx.x * 13 + cls];
    const float gcx = s_gb[g * 4 + 0], gcy = s_gb[g * 4 + 1];
    const float gw  = s_gb[g * 4 + 2], gh  = s_gb[g * 4 + 3];
    const float l1 = fabsf(pcx - gcx) + fabsf(pcy - gcy) + fabsf(pw - gw) + fabsf(ph - gh);
    const float gx1 = gcx - 0.5f * gw, gy1 = gcy - 0.5f * gh;
    const float gx2 = gcx + 0.5f * gw, gy2 = gcy + 0.5f * gh;
    const float ga = fmaxf(gx2 - gx1, 0.f) * fmaxf(gy2 - gy1, 0.f);
    const float ltx = fmaxf(px1, gx1), lty = fmaxf(py1, gy1);
    const float rbx = fminf(px2, gx2), rby = fminf(py2, gy2);
    const float iw = fmaxf(rbx - ltx, 0.f), ih = fmaxf(rby - lty, 0.f);
    const float inter = iw * ih;
    const float uni = pa + ga - inter;
    const float iou = inter / fmaxf(uni, 1e-6f);
    const float ex1 = fminf(px1, gx1), ey1 = fminf(py1, gy1);
    const float ex2 = fmaxf(px2, gx2), ey2 = fmaxf(py2, gy2);
    const float ew = fmaxf(ex2 - ex1, 0.f), eh = fmaxf(ey2 - ey1, 0.f);
    const float enc = ew * eh;
    const float giou = iou - (enc - uni) / fmaxf(enc, 1e-6f);
    crow[(size_t)g * QQ] = CLS_W * cc + L1_W * l1 - GIOU_W * giou;
  }
}

// ---------------- Jonker-Volgenant per batch (exact match of reference hungarian) ----------------
#define MM QQ   // columns (queries), rows = nvalid (<= GG)

__global__ __launch_bounds__(256) void jv_kernel(
    const int* __restrict__ gcls, const float* __restrict__ cost,
    int* __restrict__ match_g) {
  const int b = blockIdx.x;
  const int tid = threadIdx.x;

  __shared__ double u[GG + 1];
  __shared__ double v[MM + 1];
  __shared__ double minv[MM + 1];
  __shared__ int    p[MM + 1];
  __shared__ int    way[MM + 1];
  __shared__ unsigned char used[MM + 1];
  __shared__ int sh_j0, sh_i0, sh_j1, sh_done, sh_n;
  __shared__ double sh_delta;
  __shared__ double red_v[4];
  __shared__ int    red_i[4];

  if (tid == 0) {
    int n = 0;
    for (int g = 0; g < GG; ++g) if (gcls[b * GG + g] >= 0) ++n;
    sh_n = n;
  }
  for (int j = tid; j <= MM; j += 256) { v[j] = 0.0; p[j] = 0; }
  for (int r = tid; r <= GG; r += 256) u[r] = 0.0;
  __syncthreads();

  const int n = sh_n;
  const float* Cb = cost + (size_t)b * GG * QQ;

  for (int i = 1; i <= n; ++i) {
    if (tid == 0) { p[0] = i; sh_j0 = 0; }
    for (int j = tid; j <= MM; j += 256) { minv[j] = 1e300; way[j] = 0; used[j] = 0; }
    __syncthreads();

    while (true) {
      const int j0 = sh_j0;
      if (tid == 0) { used[j0] = 1; sh_i0 = p[j0]; }
      __syncthreads();
      const int i0 = sh_i0;
      const double ui0 = u[i0];
      const float* Crow = Cb + (size_t)(i0 - 1) * QQ;

      double lval = 1e301;
      int lidx = MM + 1;
      for (int j = 1 + tid; j <= MM; j += 256) {
        if (!used[j]) {
          const double cur = (double)Crow[j - 1] - ui0 - v[j];
          if (cur < minv[j]) { minv[j] = cur; way[j] = j0; }
          const double mv = minv[j];
          if (mv < lval) { lval = mv; lidx = j; }  // ascending j: keeps first min
        }
      }
      // wave argmin (tie -> smaller index, matches np.argmin first-index)
      for (int off = 32; off; off >>= 1) {
        const double ov = __shfl_down(lval, off);
        const int oi = __shfl_down(lidx, off);
        if (ov < lval || (ov == lval && oi < lidx)) { lval = ov; lidx = oi; }
      }
      const int wv = tid >> 6;
      if ((tid & 63) == 0) { red_v[wv] = lval; red_i[wv] = lidx; }
      __syncthreads();
      if (tid == 0) {
        double bv = red_v[0]; int bi = red_i[0];
        for (int w2 = 1; w2 < 4; ++w2) {
          const double ov = red_v[w2]; const int oi = red_i[w2];
          if (ov < bv || (ov == bv && oi < bi)) { bv = ov; bi = oi; }
        }
        sh_j1 = bi; sh_delta = bv;
      }
      __syncthreads();
      const int j1 = sh_j1;
      const double delta = sh_delta;
      for (int j = tid; j <= MM; j += 256) {
        if (used[j]) { u[p[j]] += delta; v[j] -= delta; }
        else minv[j] -= delta;
      }
      if (tid == 0) { sh_j0 = j1; sh_done = (p[j1] == 0); }
      __syncthreads();
      if (sh_done) break;
    }
    // augment (thread 0, short dependent chain over LDS)
    if (tid == 0) {
      int j0 = sh_j0;
      while (j0) { const int jn = way[j0]; p[j0] = p[jn]; j0 = jn; }
    }
    __syncthreads();
  }

  for (int j = 1 + tid; j <= MM; j += 256) match_g[b * QQ + (j - 1)] = p[j] - 1;
}

// ---------------- loss ----------------
__global__ __launch_bounds__(256) void loss_kernel(
    const float* __restrict__ logits, const float* __restrict__ pboxes,
    const int* __restrict__ gcls, const float* __restrict__ gboxes,
    const int* __restrict__ match_g, Accum* acc) {
  const int idx = blockIdx.x * 256 + threadIdx.x;   // B*Q = 57600 = 225*256 exactly
  const int b = idx / QQ;
  const int q = idx - b * QQ;
  (void)q;

  double wnll = 0.0, wt = 0.0, l1d = 0.0, gld = 0.0;
  int nm = 0;
  {
    const float* lg = logits + (size_t)idx * CP1;
    float l[CP1];
    float mx = -1e30f;
    for (int c = 0; c < CP1; ++c) { l[c] = lg[c]; mx = fmaxf(mx, l[c]); }
    float se = 0.f;
    for (int c = 0; c < CP1; ++c) se += expf(l[c] - mx);
    const float lse = logf(se);
    const int g = match_g[idx];
    const int t = (g >= 0) ? gcls[b * GG + g] : NCLS;
    float lt = l[0];
    for (int c = 1; c < CP1; ++c) lt = (c == t) ? l[c] : lt;
    const float logp = (lt - mx) - lse;
    const float w = (t == NCLS) ? 0.1f : 1.0f;
    wnll = (double)(w * (-logp));
    wt = (double)w;
    if (g >= 0) {
      nm = 1;
      const float* pb = pboxes + (size_t)idx * 4;
      const float* gb = gboxes + ((size_t)b * GG + g) * 4;
      const float pcx = pb[0], pcy = pb[1], pw = pb[2], ph = pb[3];
      const float gcx = gb[0], gcy = gb[1], gw = gb[2], gh = gb[3];
      const float l1 = fabsf(pcx - gcx) + fabsf(pcy - gcy) + fabsf(pw - gw) + fabsf(ph - gh);
      const float px1 = pcx - 0.5f * pw, py1 = pcy - 0.5f * ph;
      const float px2 = pcx + 0.5f * pw, py2 = pcy + 0.5f * ph;
      const float gx1 = gcx - 0.5f * gw, gy1 = gcy - 0.5f * gh;
      const float gx2 = gcx + 0.5f * gw, gy2 = gcy + 0.5f * gh;
      const float pa = fmaxf(px2 - px1, 0.f) * fmaxf(py2 - py1, 0.f);
      const float ga = fmaxf(gx2 - gx1, 0.f) * fmaxf(gy2 - gy1, 0.f);
      const float ltx = fmaxf(px1, gx1), lty = fmaxf(py1, gy1);
      const float rbx = fminf(px2, gx2), rby = fminf(py2, gy2);
      const float iw = fmaxf(rbx - ltx, 0.f), ih = fmaxf(rby - lty, 0.f);
      const float inter = iw * ih;
      const float uni = pa + ga - inter;
      const float iou = inter / fmaxf(uni, 1e-6f);
      const float ex1 = fminf(px1, gx1), ey1 = fminf(py1, gy1);
      const float ex2 = fmaxf(px2, gx2), ey2 = fmaxf(py2, gy2);
      const float ew = fmaxf(ex2 - ex1, 0.f), eh = fmaxf(ey2 - ey1, 0.f);
      const float enc = ew * eh;
      const float giou = iou - (enc - uni) / fmaxf(enc, 1e-6f);
      l1d = (double)l1;
      gld = (double)(1.0f - giou);
    }
  }

  for (int off = 32; off; off >>= 1) {
    wnll += __shfl_down(wnll, off);
    wt   += __shfl_down(wt, off);
    l1d  += __shfl_down(l1d, off);
    gld  += __shfl_down(gld, off);
    nm   += __shfl_down(nm, off);
  }
  __shared__ double r0[4], r1[4], r2[4], r3[4];
  __shared__ int r4[4];
  const int wv = threadIdx.x >> 6;
  if ((threadIdx.x & 63) == 0) { r0[wv] = wnll; r1[wv] = wt; r2[wv] = l1d; r3[wv] = gld; r4[wv] = nm; }
  __syncthreads();
  if (threadIdx.x == 0) {
    for (int w2 = 1; w2 < 4; ++w2) { wnll += r0[w2]; wt += r1[w2]; l1d += r2[w2]; gld += r3[w2]; nm += r4[w2]; }
    atomicAdd(&acc->wnll, wnll);
    atomicAdd(&acc->wt, wt);
    atomicAdd(&acc->l1, l1d);
    atomicAdd(&acc->gl, gld);
    atomicAdd(&acc->nm, nm);
  }
}

// ---------------- finalize ----------------
__global__ void finalize_kernel(const Accum* acc, float* out) {
  const double cls_loss = acc->wnll / acc->wt;
  const int nm = acc->nm > 0 ? acc->nm : 1;
  const double loss = (double)CLS_W * cls_loss +
                      ((double)L1_W * acc->l1 + (double)GIOU_W * acc->gl) / (double)nm;
  out[0] = (float)loss;
}

extern "C" void kernel_launch(void* const* d_in, const int* in_sizes, int n_in,
                              void* d_out, int out_size, void* d_ws, size_t ws_size,
                              hipStream_t stream) {
  const float* logits = (const float*)d_in[0];
  const float* pboxes = (const float*)d_in[1];
  const int*   gcls   = (const int*)d_in[2];
  const float* gboxes = (const float*)d_in[3];

  char* ws = (char*)d_ws;
  Accum* acc = (Accum*)ws;                                  // 64 B
  int* match_g = (int*)(ws + 64);                           // B*Q ints = 230400 B
  float* cost = (float*)(ws + 64 + (size_t)BB * QQ * 4);    // B*G*Q floats = 23 MB

  init_kernel<<<1, 64, 0, stream>>>(acc);
  cost_kernel<<<dim3((QQ + 255) / 256, BB), 256, 0, stream>>>(logits, pboxes, gcls, gboxes, cost);
  jv_kernel<<<BB, 256, 0, stream>>>(gcls, cost, match_g);
  loss_kernel<<<(BB * QQ) / 256, 256, 0, stream>>>(logits, pboxes, gcls, gboxes, match_g, acc);
  finalize_kernel<<<1, 1, 0, stream>>>(acc, (float*)d_out);
}

// Round 2
// 337.114 us; speedup vs baseline: 1.3207x; 1.3207x over previous
//
#include <hip/hip_runtime.h>
#include <hip/hip_bf16.h>
#include <math.h>

#define BB 64
#define QQ 900
#define GG 100
#define NCLS 10
#define CP1 11

#define STRIDE 960   // 64*15: every lane owns exactly KPL columns; cols 900..959 are +inf pads
#define KPL 15

#define CLS_W 2.0f
#define L1_W 5.0f
#define GIOU_W 2.0f

struct Accum {
  double wnll;   // sum w * nll
  double wt;     // sum w
  double l1;     // sum |dbox|
  double gl;     // sum (1 - giou)
  int nm;        // matched count
  int counter;   // completion ticket for fused finalize
  int pad[6];
};

// ---------------- cost matrix: cost[b][g][q], row stride 960 (pads = 1e30) ----------------
__global__ __launch_bounds__(256) void cost_kernel(
    const float* __restrict__ logits, const float* __restrict__ pboxes,
    const int* __restrict__ gcls, const float* __restrict__ gboxes,
    float* __restrict__ cost, Accum* acc) {
  const int b = blockIdx.y;
  const int q = blockIdx.x * 256 + threadIdx.x;

  if (blockIdx.x == 0 && blockIdx.y == 0 && threadIdx.x == 0) {
    acc->wnll = 0.0; acc->wt = 0.0; acc->l1 = 0.0; acc->gl = 0.0;
    acc->nm = 0; acc->counter = 0;
  }

  __shared__ float s_gb[GG * 4];
  __shared__ int   s_gc[GG];
  __shared__ float s_prob[256 * 13];

  for (int i = threadIdx.x; i < GG * 4; i += 256) s_gb[i] = gboxes[b * GG * 4 + i];
  for (int i = threadIdx.x; i < GG; i += 256)     s_gc[i] = gcls[b * GG + i];

  float pcx = 0.f, pcy = 0.f, pw = 0.f, ph = 0.f;
  if (q < QQ) {
    const float* lg = logits + ((size_t)b * QQ + q) * CP1;
    float l[CP1];
    float mx = -1e30f;
    for (int c = 0; c < CP1; ++c) { l[c] = lg[c]; mx = fmaxf(mx, l[c]); }
    float se = 0.f;
    for (int c = 0; c < CP1; ++c) { l[c] = expf(l[c] - mx); se += l[c]; }
    float inv = 1.0f / se;
    for (int c = 0; c < CP1; ++c) s_prob[threadIdx.x * 13 + c] = l[c] * inv;
    const float* pb = pboxes + ((size_t)b * QQ + q) * 4;
    pcx = pb[0]; pcy = pb[1]; pw = pb[2]; ph = pb[3];
  }
  __syncthreads();
  if (q >= STRIDE) return;

  float* crow = cost + ((size_t)b * GG) * STRIDE + q;
  if (q >= QQ) {  // pad columns: huge cost, never selected
    for (int g = 0; g < GG; ++g) crow[(size_t)g * STRIDE] = 1e30f;
    return;
  }

  const float px1 = pcx - 0.5f * pw, py1 = pcy - 0.5f * ph;
  const float px2 = pcx + 0.5f * pw, py2 = pcy + 0.5f * ph;
  const float pa = fmaxf(px2 - px1, 0.f) * fmaxf(py2 - py1, 0.f);

  for (int g = 0; g < GG; ++g) {
    int cls = s_gc[g];
    cls = cls < 0 ? 0 : (cls > NCLS - 1 ? NCLS - 1 : cls);
    const float cc = -s_prob[threadIdx.x * 13 + cls];
    const float gcx = s_gb[g * 4 + 0], gcy = s_gb[g * 4 + 1];
    const float gw  = s_gb[g * 4 + 2], gh  = s_gb[g * 4 + 3];
    const float l1 = fabsf(pcx - gcx) + fabsf(pcy - gcy) + fabsf(pw - gw) + fabsf(ph - gh);
    const float gx1 = gcx - 0.5f * gw, gy1 = gcy - 0.5f * gh;
    const float gx2 = gcx + 0.5f * gw, gy2 = gcy + 0.5f * gh;
    const float ga = fmaxf(gx2 - gx1, 0.f) * fmaxf(gy2 - gy1, 0.f);
    const float ltx = fmaxf(px1, gx1), lty = fmaxf(py1, gy1);
    const float rbx = fminf(px2, gx2), rby = fminf(py2, gy2);
    const float iw = fmaxf(rbx - ltx, 0.f), ih = fmaxf(rby - lty, 0.f);
    const float inter = iw * ih;
    const float uni = pa + ga - inter;
    const float iou = inter / fmaxf(uni, 1e-6f);
    const float ex1 = fminf(px1, gx1), ey1 = fminf(py1, gy1);
    const float ex2 = fmaxf(px2, gx2), ey2 = fmaxf(py2, gy2);
    const float ew = fmaxf(ex2 - ex1, 0.f), eh = fmaxf(ey2 - ey1, 0.f);
    const float enc = ew * eh;
    const float giou = iou - (enc - uni) / fmaxf(enc, 1e-6f);
    crow[(size_t)g * STRIDE] = CLS_W * cc + L1_W * l1 - GIOU_W * giou;
  }
}

// ---------------- Jonker-Volgenant: one wave per batch, column state in registers ----------------
__global__ __launch_bounds__(64) void jv_kernel(
    const int* __restrict__ gcls, const float* __restrict__ cost,
    int* __restrict__ match_g) {
  const int b = blockIdx.x;
  const int lane = threadIdx.x;

  __shared__ double u[GG + 2];
  __shared__ int p[QQ + 1];
  __shared__ int way[STRIDE + 1];
  __shared__ int tree_rows[GG + 2];
  __shared__ int sh_n;

  {
    int c = 0;
    for (int g = lane; g < GG; g += 64) c += (gcls[b * GG + g] >= 0) ? 1 : 0;
    for (int off = 32; off; off >>= 1) c += __shfl_down(c, off);
    if (lane == 0) sh_n = c;
  }
  for (int j = lane; j <= QQ; j += 64) p[j] = 0;
  for (int r = lane; r <= GG + 1; r += 64) u[r] = 0.0;
  __syncthreads();

  const int n = sh_n;
  const float* Cb = cost + (size_t)b * GG * STRIDE;

  double v[KPL], minv[KPL];
  float rc[KPL];
#pragma unroll
  for (int k = 0; k < KPL; ++k) v[k] = 0.0;

  for (int i = 1; i <= n; ++i) {
#pragma unroll
    for (int k = 0; k < KPL; ++k) minv[k] = 1e300;
    unsigned int usedm = 0;
    int j0 = 0, i0 = i, t = 0;
    if (lane == 0) p[0] = i;
    double ui0 = 0.0;  // u[i] == 0: row i has never been in any tree
    // prefetch row i
    {
      const float* Cr = Cb + (size_t)(i - 1) * STRIDE + lane;
#pragma unroll
      for (int k = 0; k < KPL; ++k) rc[k] = Cr[64 * k];
    }
    int j1;

    while (true) {
      // mark used[j0] (j0==0 is the dummy column, tracked only via tree_rows)
      if (j0 > 0) { const int c = j0 - 1; if ((c & 63) == lane) usedm |= 1u << (c >> 6); }
      if (lane == 0) tree_rows[t] = i0;
      t++;

      // scan own columns: cur = C - u[i0] - v[j]; update minv/way; local argmin
      double lval = 1e301; int lidx = 0x3FFFFFFF;
#pragma unroll
      for (int k = 0; k < KPL; ++k) {
        const bool us = (usedm >> k) & 1u;
        const double cur = (double)rc[k] - ui0 - v[k];
        if (!us && cur < minv[k]) { minv[k] = cur; way[1 + lane + 64 * k] = j0; }
        const double mv = us ? 1e301 : minv[k];
        if (mv < lval) { lval = mv; lidx = 1 + lane + 64 * k; }
      }
      // butterfly all-reduce argmin; tie -> smallest j (np.argmin first-index)
      for (int m = 1; m < 64; m <<= 1) {
        const double ov = __shfl_xor(lval, m);
        const int oi = __shfl_xor(lidx, m);
        if (ov < lval || (ov == lval && oi < lidx)) { lval = ov; lidx = oi; }
      }
      const double delta = lval;
      j1 = lidx;

      __syncthreads();  // single-wave: s_barrier elided; orders tree_rows/way writes vs reads

      // dual updates (reference order: u[tree]+=d, v[used]-=d, minv[unused]-=d)
      for (int s = lane; s < t; s += 64) u[tree_rows[s]] += delta;
#pragma unroll
      for (int k = 0; k < KPL; ++k) {
        if ((usedm >> k) & 1u) v[k] -= delta; else minv[k] -= delta;
      }

      const int i0n = p[j1];
      if (i0n == 0) break;
      // i0n is not in the tree -> u[i0n] untouched by this row's scatters: safe to read now
      ui0 = u[i0n];
      {  // prefetch next row while finishing this step
        const float* Cr = Cb + (size_t)(i0n - 1) * STRIDE + lane;
#pragma unroll
        for (int k = 0; k < KPL; ++k) rc[k] = Cr[64 * k];
      }
      j0 = j1; i0 = i0n;
    }

    // augment (lane 0; way writes all precede the final step's barrier)
    if (lane == 0) {
      int jj = j1;
      while (jj) { const int jn = way[jj]; p[jj] = p[jn]; jj = jn; }
    }
    __syncthreads();
  }

  for (int j = 1 + lane; j <= QQ; j += 64) match_g[b * QQ + (j - 1)] = p[j] - 1;
}

// ---------------- loss (+fused finalize via ticket) ----------------
__global__ __launch_bounds__(256) void loss_kernel(
    const float* __restrict__ logits, const float* __restrict__ pboxes,
    const int* __restrict__ gcls, const float* __restrict__ gboxes,
    const int* __restrict__ match_g, Accum* acc, float* out, int nblocks) {
  const int idx = blockIdx.x * 256 + threadIdx.x;   // B*Q = 57600 = 225*256
  const int b = idx / QQ;

  double wnll, wt, l1d = 0.0, gld = 0.0;
  int nm = 0;
  {
    const float* lg = logits + (size_t)idx * CP1;
    float l[CP1];
    float mx = -1e30f;
    for (int c = 0; c < CP1; ++c) { l[c] = lg[c]; mx = fmaxf(mx, l[c]); }
    float se = 0.f;
    for (int c = 0; c < CP1; ++c) se += expf(l[c] - mx);
    const float lse = logf(se);
    const int g = match_g[idx];
    const int t = (g >= 0) ? gcls[b * GG + g] : NCLS;
    float lt = l[0];
    for (int c = 1; c < CP1; ++c) lt = (c == t) ? l[c] : lt;
    const float logp = (lt - mx) - lse;
    const float w = (t == NCLS) ? 0.1f : 1.0f;
    wnll = (double)(w * (-logp));
    wt = (double)w;
    if (g >= 0) {
      nm = 1;
      const float* pb = pboxes + (size_t)idx * 4;
      const float* gb = gboxes + ((size_t)b * GG + g) * 4;
      const float pcx = pb[0], pcy = pb[1], pw = pb[2], ph = pb[3];
      const float gcx = gb[0], gcy = gb[1], gw = gb[2], gh = gb[3];
      const float l1 = fabsf(pcx - gcx) + fabsf(pcy - gcy) + fabsf(pw - gw) + fabsf(ph - gh);
      const float px1 = pcx - 0.5f * pw, py1 = pcy - 0.5f * ph;
      const float px2 = pcx + 0.5f * pw, py2 = pcy + 0.5f * ph;
      const float gx1 = gcx - 0.5f * gw, gy1 = gcy - 0.5f * gh;
      const float gx2 = gcx + 0.5f * gw, gy2 = gcy + 0.5f * gh;
      const float pa = fmaxf(px2 - px1, 0.f) * fmaxf(py2 - py1, 0.f);
      const float ga = fmaxf(gx2 - gx1, 0.f) * fmaxf(gy2 - gy1, 0.f);
      const float ltx = fmaxf(px1, gx1), lty = fmaxf(py1, gy1);
      const float rbx = fminf(px2, gx2), rby = fminf(py2, gy2);
      const float iw = fmaxf(rbx - ltx, 0.f), ih = fmaxf(rby - lty, 0.f);
      const float inter = iw * ih;
      const float uni = pa + ga - inter;
      const float iou = inter / fmaxf(uni, 1e-6f);
      const float ex1 = fminf(px1, gx1), ey1 = fminf(py1, gy1);
      const float ex2 = fmaxf(px2, gx2), ey2 = fmaxf(py2, gy2);
      const float ew = fmaxf(ex2 - ex1, 0.f), eh = fmaxf(ey2 - ey1, 0.f);
      const float enc = ew * eh;
      const float giou = iou - (enc - uni) / fmaxf(enc, 1e-6f);
      l1d = (double)l1;
      gld = (double)(1.0f - giou);
    }
  }

  for (int off = 32; off; off >>= 1) {
    wnll += __shfl_down(wnll, off);
    wt   += __shfl_down(wt, off);
    l1d  += __shfl_down(l1d, off);
    gld  += __shfl_down(gld, off);
    nm   += __shfl_down(nm, off);
  }
  __shared__ double r0[4], r1[4], r2[4], r3[4];
  __shared__ int r4[4];
  const int wv = threadIdx.x >> 6;
  if ((threadIdx.x & 63) == 0) { r0[wv] = wnll; r1[wv] = wt; r2[wv] = l1d; r3[wv] = gld; r4[wv] = nm; }
  __syncthreads();
  if (threadIdx.x == 0) {
    for (int w2 = 1; w2 < 4; ++w2) { wnll += r0[w2]; wt += r1[w2]; l1d += r2[w2]; gld += r3[w2]; nm += r4[w2]; }
    atomicAdd(&acc->wnll, wnll);
    atomicAdd(&acc->wt, wt);
    atomicAdd(&acc->l1, l1d);
    atomicAdd(&acc->gl, gld);
    atomicAdd(&acc->nm, nm);
    __threadfence();
    const int ticket = atomicAdd(&acc->counter, 1);
    if (ticket == nblocks - 1) {
      const double fw = atomicAdd(&acc->wnll, 0.0);
      const double fwt = atomicAdd(&acc->wt, 0.0);
      const double fl1 = atomicAdd(&acc->l1, 0.0);
      const double fgl = atomicAdd(&acc->gl, 0.0);
      int fnm = atomicAdd(&acc->nm, 0);
      if (fnm < 1) fnm = 1;
      const double loss = (double)CLS_W * (fw / fwt) +
                          ((double)L1_W * fl1 + (double)GIOU_W * fgl) / (double)fnm;
      out[0] = (float)loss;
    }
  }
}

extern "C" void kernel_launch(void* const* d_in, const int* in_sizes, int n_in,
                              void* d_out, int out_size, void* d_ws, size_t ws_size,
                              hipStream_t stream) {
  const float* logits = (const float*)d_in[0];
  const float* pboxes = (const float*)d_in[1];
  const int*   gcls   = (const int*)d_in[2];
  const float* gboxes = (const float*)d_in[3];

  char* ws = (char*)d_ws;
  Accum* acc = (Accum*)ws;                                   // 64 B
  int* match_g = (int*)(ws + 128);                           // B*Q ints
  float* cost = (float*)(ws + 128 + (size_t)BB * QQ * 4);    // B*G*960 floats ~ 24.6 MB

  cost_kernel<<<dim3((STRIDE + 255) / 256, BB), 256, 0, stream>>>(logits, pboxes, gcls, gboxes, cost, acc);
  jv_kernel<<<BB, 64, 0, stream>>>(gcls, cost, match_g);
  const int nblocks = (BB * QQ) / 256;
  loss_kernel<<<nblocks, 256, 0, stream>>>(logits, pboxes, gcls, gboxes, match_g, acc, (float*)d_out, nblocks);
}

// Round 3
// 226.468 us; speedup vs baseline: 1.9659x; 1.4886x over previous
//
#include <hip/hip_runtime.h>
#include <hip/hip_bf16.h>
#include <math.h>

#define BB 64
#define QQ 900
#define GG 100
#define NCLS 10
#define CP1 11

#define STRIDE 960   // 64*15: every lane owns exactly KPL columns; cols 900..959 are +inf pads
#define KPL 15

#define CLS_W 2.0f
#define L1_W 5.0f
#define GIOU_W 2.0f

struct Accum {
  double wnll;   // sum w * nll
  double wt;     // sum w
  double l1;     // sum |dbox|
  double gl;     // sum (1 - giou)
  int nm;        // matched count
  int counter;   // completion ticket for fused finalize
  int pad[6];
};

// ---------------- cost matrix: cost[b][g][q], row stride 960 (pads = 1e30) ----------------
__global__ __launch_bounds__(256) void cost_kernel(
    const float* __restrict__ logits, const float* __restrict__ pboxes,
    const int* __restrict__ gcls, const float* __restrict__ gboxes,
    float* __restrict__ cost, Accum* acc) {
  const int b = blockIdx.y;
  const int q = blockIdx.x * 256 + threadIdx.x;

  if (blockIdx.x == 0 && blockIdx.y == 0 && threadIdx.x == 0) {
    acc->wnll = 0.0; acc->wt = 0.0; acc->l1 = 0.0; acc->gl = 0.0;
    acc->nm = 0; acc->counter = 0;
  }

  __shared__ float s_gb[GG * 4];
  __shared__ int   s_gc[GG];
  __shared__ float s_prob[256 * 13];

  for (int i = threadIdx.x; i < GG * 4; i += 256) s_gb[i] = gboxes[b * GG * 4 + i];
  for (int i = threadIdx.x; i < GG; i += 256)     s_gc[i] = gcls[b * GG + i];

  float pcx = 0.f, pcy = 0.f, pw = 0.f, ph = 0.f;
  if (q < QQ) {
    const float* lg = logits + ((size_t)b * QQ + q) * CP1;
    float l[CP1];
    float mx = -1e30f;
    for (int c = 0; c < CP1; ++c) { l[c] = lg[c]; mx = fmaxf(mx, l[c]); }
    float se = 0.f;
    for (int c = 0; c < CP1; ++c) { l[c] = expf(l[c] - mx); se += l[c]; }
    float inv = 1.0f / se;
    for (int c = 0; c < CP1; ++c) s_prob[threadIdx.x * 13 + c] = l[c] * inv;
    const float* pb = pboxes + ((size_t)b * QQ + q) * 4;
    pcx = pb[0]; pcy = pb[1]; pw = pb[2]; ph = pb[3];
  }
  __syncthreads();
  if (q >= STRIDE) return;

  float* crow = cost + ((size_t)b * GG) * STRIDE + q;
  if (q >= QQ) {  // pad columns: huge cost, never selected
    for (int g = 0; g < GG; ++g) crow[(size_t)g * STRIDE] = 1e30f;
    return;
  }

  const float px1 = pcx - 0.5f * pw, py1 = pcy - 0.5f * ph;
  const float px2 = pcx + 0.5f * pw, py2 = pcy + 0.5f * ph;
  const float pa = fmaxf(px2 - px1, 0.f) * fmaxf(py2 - py1, 0.f);

  for (int g = 0; g < GG; ++g) {
    int cls = s_gc[g];
    cls = cls < 0 ? 0 : (cls > NCLS - 1 ? NCLS - 1 : cls);
    const float cc = -s_prob[threadIdx.x * 13 + cls];
    const float gcx = s_gb[g * 4 + 0], gcy = s_gb[g * 4 + 1];
    const float gw  = s_gb[g * 4 + 2], gh  = s_gb[g * 4 + 3];
    const float l1 = fabsf(pcx - gcx) + fabsf(pcy - gcy) + fabsf(pw - gw) + fabsf(ph - gh);
    const float gx1 = gcx - 0.5f * gw, gy1 = gcy - 0.5f * gh;
    const float gx2 = gcx + 0.5f * gw, gy2 = gcy + 0.5f * gh;
    const float ga = fmaxf(gx2 - gx1, 0.f) * fmaxf(gy2 - gy1, 0.f);
    const float ltx = fmaxf(px1, gx1), lty = fmaxf(py1, gy1);
    const float rbx = fminf(px2, gx2), rby = fminf(py2, gy2);
    const float iw = fmaxf(rbx - ltx, 0.f), ih = fmaxf(rby - lty, 0.f);
    const float inter = iw * ih;
    const float uni = pa + ga - inter;
    const float iou = inter / fmaxf(uni, 1e-6f);
    const float ex1 = fminf(px1, gx1), ey1 = fminf(py1, gy1);
    const float ex2 = fmaxf(px2, gx2), ey2 = fmaxf(py2, gy2);
    const float ew = fmaxf(ex2 - ex1, 0.f), eh = fmaxf(ey2 - ey1, 0.f);
    const float enc = ew * eh;
    const float giou = iou - (enc - uni) / fmaxf(enc, 1e-6f);
    crow[(size_t)g * STRIDE] = CLS_W * cc + L1_W * l1 - GIOU_W * giou;
  }
}

// ---------------- JV (greedy row-reduction init + Dijkstra) + fused loss ----------------
__global__ __launch_bounds__(64) void jv_kernel(
    const float* __restrict__ logits, const float* __restrict__ pboxes,
    const int* __restrict__ gcls, const float* __restrict__ gboxes,
    const float* __restrict__ cost, Accum* acc, float* out) {
  const int b = blockIdx.x;
  const int lane = threadIdx.x;

  __shared__ double u[GG + 2];
  __shared__ int p[QQ + 1];
  __shared__ int way[STRIDE + 1];
  __shared__ int tree_rows[GG + 2];
  __shared__ int rowmin_j[GG + 2];
  __shared__ int unmatched[GG + 1];
  __shared__ int sh_n, sh_nu;

  {
    int c = 0;
    for (int g = lane; g < GG; g += 64) c += (gcls[b * GG + g] >= 0) ? 1 : 0;
    for (int off = 32; off; off >>= 1) c += __shfl_down(c, off);
    if (lane == 0) sh_n = c;
  }
  for (int j = lane; j <= QQ; j += 64) p[j] = 0;
  __syncthreads();

  const int n = sh_n;
  const float* Cb = cost + (size_t)b * GG * STRIDE;

  // ---- Phase 1: row reduction u[i] = min_j C[i,j], argmin per row (pairs for ILP) ----
  for (int i = 1; i <= n; i += 2) {
    const bool two = (i < n);
    float rcA[KPL], rcB[KPL];
    const float* CrA = Cb + (size_t)(i - 1) * STRIDE + lane;
    const float* CrB = Cb + (size_t)i * STRIDE + lane;
#pragma unroll
    for (int k = 0; k < KPL; ++k) rcA[k] = CrA[64 * k];
    if (two) {
#pragma unroll
      for (int k = 0; k < KPL; ++k) rcB[k] = CrB[64 * k];
    } else {
#pragma unroll
      for (int k = 0; k < KPL; ++k) rcB[k] = 1e30f;
    }
    double lvA = 1e301, lvB = 1e301;
    int liA = 0x3FFFFFFF, liB = 0x3FFFFFFF;
#pragma unroll
    for (int k = 0; k < KPL; ++k) {
      const double a = (double)rcA[k];
      if (a < lvA) { lvA = a; liA = 1 + lane + 64 * k; }
      const double c = (double)rcB[k];
      if (c < lvB) { lvB = c; liB = 1 + lane + 64 * k; }
    }
    for (int m = 1; m < 64; m <<= 1) {
      const double ovA = __shfl_xor(lvA, m); const int oiA = __shfl_xor(liA, m);
      if (ovA < lvA || (ovA == lvA && oiA < liA)) { lvA = ovA; liA = oiA; }
      const double ovB = __shfl_xor(lvB, m); const int oiB = __shfl_xor(liB, m);
      if (ovB < lvB || (ovB == lvB && oiB < liB)) { lvB = ovB; liB = oiB; }
    }
    if (lane == 0) {
      u[i] = lvA; rowmin_j[i] = liA;
      if (two) { u[i + 1] = lvB; rowmin_j[i + 1] = liB; }
    }
  }
  __syncthreads();

  // ---- greedy claim ----
  if (lane == 0) {
    int nu = 0;
    for (int i = 1; i <= n; ++i) {
      const int j = rowmin_j[i];
      if (p[j] == 0) p[j] = i;
      else unmatched[nu++] = i;
    }
    sh_nu = nu;
  }
  __syncthreads();
  const int nu = sh_nu;

  // ---- Phase 2: Dijkstra augmentation for collided rows ----
  double v[KPL], minv[KPL];
  float rc[KPL];
#pragma unroll
  for (int k = 0; k < KPL; ++k) v[k] = 0.0;

  for (int ii = 0; ii < nu; ++ii) {
    const int i = unmatched[ii];
#pragma unroll
    for (int k = 0; k < KPL; ++k) minv[k] = 1e300;
    unsigned int usedm = 0;
    int j0 = 0, i0 = i, t = 0;
    if (lane == 0) p[0] = i;
    double ui0 = u[i];
    {
      const float* Cr = Cb + (size_t)(i - 1) * STRIDE + lane;
#pragma unroll
      for (int k = 0; k < KPL; ++k) rc[k] = Cr[64 * k];
    }
    int j1;

    while (true) {
      if (j0 > 0) { const int c = j0 - 1; if ((c & 63) == lane) usedm |= 1u << (c >> 6); }
      if (lane == 0) tree_rows[t] = i0;
      t++;

      double lval = 1e301; int lidx = 0x3FFFFFFF;
#pragma unroll
      for (int k = 0; k < KPL; ++k) {
        const bool us = (usedm >> k) & 1u;
        const double cur = (double)rc[k] - ui0 - v[k];
        if (!us && cur < minv[k]) { minv[k] = cur; way[1 + lane + 64 * k] = j0; }
        const double mv = us ? 1e301 : minv[k];
        if (mv < lval) { lval = mv; lidx = 1 + lane + 64 * k; }
      }
      for (int m = 1; m < 64; m <<= 1) {
        const double ov = __shfl_xor(lval, m);
        const int oi = __shfl_xor(lidx, m);
        if (ov < lval || (ov == lval && oi < lidx)) { lval = ov; lidx = oi; }
      }
      const double delta = lval;
      j1 = lidx;

      __syncthreads();

      for (int s = lane; s < t; s += 64) u[tree_rows[s]] += delta;
#pragma unroll
      for (int k = 0; k < KPL; ++k) {
        if ((usedm >> k) & 1u) v[k] -= delta; else minv[k] -= delta;
      }

      const int i0n = p[j1];
      if (i0n == 0) break;
      ui0 = u[i0n];
      {
        const float* Cr = Cb + (size_t)(i0n - 1) * STRIDE + lane;
#pragma unroll
        for (int k = 0; k < KPL; ++k) rc[k] = Cr[64 * k];
      }
      j0 = j1; i0 = i0n;
    }

    if (lane == 0) {
      int jj = j1;
      while (jj) { const int jn = way[jj]; p[jj] = p[jn]; jj = jn; }
    }
    __syncthreads();
  }

  // ---- fused loss over this batch's 900 queries ----
  double wnll = 0.0, wt = 0.0, l1d = 0.0, gld = 0.0;
  int nm = 0;
  for (int q = lane; q < QQ; q += 64) {
    const int idx = b * QQ + q;
    const float* lg = logits + (size_t)idx * CP1;
    float l[CP1];
    float mx = -1e30f;
    for (int c = 0; c < CP1; ++c) { l[c] = lg[c]; mx = fmaxf(mx, l[c]); }
    float se = 0.f;
    for (int c = 0; c < CP1; ++c) se += expf(l[c] - mx);
    const float lse = logf(se);
    const int g = p[q + 1] - 1;   // row index -> gt index (valid gts are a prefix)
    const int t = (g >= 0) ? gcls[b * GG + g] : NCLS;
    float lt = l[0];
    for (int c = 1; c < CP1; ++c) lt = (c == t) ? l[c] : lt;
    const float logp = (lt - mx) - lse;
    const float w = (t == NCLS) ? 0.1f : 1.0f;
    wnll += (double)(w * (-logp));
    wt += (double)w;
    if (g >= 0) {
      nm += 1;
      const float* pb = pboxes + (size_t)idx * 4;
      const float* gb = gboxes + ((size_t)b * GG + g) * 4;
      const float pcx = pb[0], pcy = pb[1], pw = pb[2], ph = pb[3];
      const float gcx = gb[0], gcy = gb[1], gw = gb[2], gh = gb[3];
      const float l1 = fabsf(pcx - gcx) + fabsf(pcy - gcy) + fabsf(pw - gw) + fabsf(ph - gh);
      const float px1 = pcx - 0.5f * pw, py1 = pcy - 0.5f * ph;
      const float px2 = pcx + 0.5f * pw, py2 = pcy + 0.5f * ph;
      const float gx1 = gcx - 0.5f * gw, gy1 = gcy - 0.5f * gh;
      const float gx2 = gcx + 0.5f * gw, gy2 = gcy + 0.5f * gh;
      const float pa = fmaxf(px2 - px1, 0.f) * fmaxf(py2 - py1, 0.f);
      const float ga = fmaxf(gx2 - gx1, 0.f) * fmaxf(gy2 - gy1, 0.f);
      const float ltx = fmaxf(px1, gx1), lty = fmaxf(py1, gy1);
      const float rbx = fminf(px2, gx2), rby = fminf(py2, gy2);
      const float iw = fmaxf(rbx - ltx, 0.f), ih = fmaxf(rby - lty, 0.f);
      const float inter = iw * ih;
      const float uni = pa + ga - inter;
      const float iou = inter / fmaxf(uni, 1e-6f);
      const float ex1 = fminf(px1, gx1), ey1 = fminf(py1, gy1);
      const float ex2 = fmaxf(px2, gx2), ey2 = fmaxf(py2, gy2);
      const float ew = fmaxf(ex2 - ex1, 0.f), eh = fmaxf(ey2 - ey1, 0.f);
      const float enc = ew * eh;
      const float giou = iou - (enc - uni) / fmaxf(enc, 1e-6f);
      l1d += (double)l1;
      gld += (double)(1.0f - giou);
    }
  }

  for (int off = 32; off; off >>= 1) {
    wnll += __shfl_down(wnll, off);
    wt   += __shfl_down(wt, off);
    l1d  += __shfl_down(l1d, off);
    gld  += __shfl_down(gld, off);
    nm   += __shfl_down(nm, off);
  }
  if (lane == 0) {
    atomicAdd(&acc->wnll, wnll);
    atomicAdd(&acc->wt, wt);
    atomicAdd(&acc->l1, l1d);
    atomicAdd(&acc->gl, gld);
    atomicAdd(&acc->nm, nm);
    __threadfence();
    const int ticket = atomicAdd(&acc->counter, 1);
    if (ticket == BB - 1) {
      const double fw = atomicAdd(&acc->wnll, 0.0);
      const double fwt = atomicAdd(&acc->wt, 0.0);
      const double fl1 = atomicAdd(&acc->l1, 0.0);
      const double fgl = atomicAdd(&acc->gl, 0.0);
      int fnm = atomicAdd(&acc->nm, 0);
      if (fnm < 1) fnm = 1;
      const double loss = (double)CLS_W * (fw / fwt) +
                          ((double)L1_W * fl1 + (double)GIOU_W * fgl) / (double)fnm;
      out[0] = (float)loss;
    }
  }
}

extern "C" void kernel_launch(void* const* d_in, const int* in_sizes, int n_in,
                              void* d_out, int out_size, void* d_ws, size_t ws_size,
                              hipStream_t stream) {
  const float* logits = (const float*)d_in[0];
  const float* pboxes = (const float*)d_in[1];
  const int*   gcls   = (const int*)d_in[2];
  const float* gboxes = (const float*)d_in[3];

  char* ws = (char*)d_ws;
  Accum* acc = (Accum*)ws;                                   // 64 B
  float* cost = (float*)(ws + 128);                          // B*G*960 floats ~ 24.6 MB

  cost_kernel<<<dim3((STRIDE + 255) / 256, BB), 256, 0, stream>>>(logits, pboxes, gcls, gboxes, cost, acc);
  jv_kernel<<<BB, 64, 0, stream>>>(logits, pboxes, gcls, gboxes, cost, acc, (float*)d_out);
}

// Round 4
// 146.378 us; speedup vs baseline: 3.0415x; 1.5471x over previous
//
#include <hip/hip_runtime.h>
#include <hip/hip_bf16.h>
#include <math.h>

#define BB 64
#define QQ 900
#define GG 100
#define NCLS 10
#define CP1 11

#define STRIDE 960   // 64*15: every lane owns exactly KPL columns; cols 900..959 are +inf pads
#define KPL 15
#define ARR_CAP 300  // bumps <= cap, so qtail <= GG + ARR_CAP < QSIZE
#define QSIZE 512

#define CLS_W 2.0f
#define L1_W 5.0f
#define GIOU_W 2.0f

struct Accum {
  double wnll, wt, l1, gl;
  int nm, counter;
  int pad[6];
};

// ---------------- cost matrix: cost[b][g][q], row stride 960 (pads = 1e30) ----------------
__global__ __launch_bounds__(256) void cost_kernel(
    const float* __restrict__ logits, const float* __restrict__ pboxes,
    const int* __restrict__ gcls, const float* __restrict__ gboxes,
    float* __restrict__ cost, Accum* acc) {
  const int b = blockIdx.y;
  const int q = blockIdx.x * 256 + threadIdx.x;

  if (blockIdx.x == 0 && blockIdx.y == 0 && threadIdx.x == 0) {
    acc->wnll = 0.0; acc->wt = 0.0; acc->l1 = 0.0; acc->gl = 0.0;
    acc->nm = 0; acc->counter = 0;
  }

  __shared__ float s_gb[GG * 4];
  __shared__ int   s_gc[GG];
  __shared__ float s_prob[256 * 13];

  for (int i = threadIdx.x; i < GG * 4; i += 256) s_gb[i] = gboxes[b * GG * 4 + i];
  for (int i = threadIdx.x; i < GG; i += 256)     s_gc[i] = gcls[b * GG + i];

  float pcx = 0.f, pcy = 0.f, pw = 0.f, ph = 0.f;
  if (q < QQ) {
    const float* lg = logits + ((size_t)b * QQ + q) * CP1;
    float l[CP1];
    float mx = -1e30f;
    for (int c = 0; c < CP1; ++c) { l[c] = lg[c]; mx = fmaxf(mx, l[c]); }
    float se = 0.f;
    for (int c = 0; c < CP1; ++c) { l[c] = expf(l[c] - mx); se += l[c]; }
    float inv = 1.0f / se;
    for (int c = 0; c < CP1; ++c) s_prob[threadIdx.x * 13 + c] = l[c] * inv;
    const float* pb = pboxes + ((size_t)b * QQ + q) * 4;
    pcx = pb[0]; pcy = pb[1]; pw = pb[2]; ph = pb[3];
  }
  __syncthreads();
  if (q >= STRIDE) return;

  float* crow = cost + ((size_t)b * GG) * STRIDE + q;
  if (q >= QQ) {  // pad columns: huge cost, never selected
    for (int g = 0; g < GG; ++g) crow[(size_t)g * STRIDE] = 1e30f;
    return;
  }

  const float px1 = pcx - 0.5f * pw, py1 = pcy - 0.5f * ph;
  const float px2 = pcx + 0.5f * pw, py2 = pcy + 0.5f * ph;
  const float pa = fmaxf(px2 - px1, 0.f) * fmaxf(py2 - py1, 0.f);

  for (int g = 0; g < GG; ++g) {
    int cls = s_gc[g];
    cls = cls < 0 ? 0 : (cls > NCLS - 1 ? NCLS - 1 : cls);
    const float cc = -s_prob[threadIdx.x * 13 + cls];
    const float gcx = s_gb[g * 4 + 0], gcy = s_gb[g * 4 + 1];
    const float gw  = s_gb[g * 4 + 2], gh  = s_gb[g * 4 + 3];
    const float l1 = fabsf(pcx - gcx) + fabsf(pcy - gcy) + fabsf(pw - gw) + fabsf(ph - gh);
    const float gx1 = gcx - 0.5f * gw, gy1 = gcy - 0.5f * gh;
    const float gx2 = gcx + 0.5f * gw, gy2 = gcy + 0.5f * gh;
    const float ga = fmaxf(gx2 - gx1, 0.f) * fmaxf(gy2 - gy1, 0.f);
    const float ltx = fmaxf(px1, gx1), lty = fmaxf(py1, gy1);
    const float rbx = fminf(px2, gx2), rby = fminf(py2, gy2);
    const float iw = fmaxf(rbx - ltx, 0.f), ih = fmaxf(rby - lty, 0.f);
    const float inter = iw * ih;
    const float uni = pa + ga - inter;
    const float iou = inter / fmaxf(uni, 1e-6f);
    const float ex1 = fminf(px1, gx1), ey1 = fminf(py1, gy1);
    const float ex2 = fmaxf(px2, gx2), ey2 = fmaxf(py2, gy2);
    const float ew = fmaxf(ex2 - ex1, 0.f), eh = fmaxf(ey2 - ey1, 0.f);
    const float enc = ew * eh;
    const float giou = iou - (enc - uni) / fmaxf(enc, 1e-6f);
    crow[(size_t)g * STRIDE] = CLS_W * cc + L1_W * l1 - GIOU_W * giou;
  }
}

// ---------------- per-row (min1, min2, argmin) — fully parallel ----------------
__global__ __launch_bounds__(64) void rowmin_kernel(
    const float* __restrict__ cost, float2* __restrict__ mins, int* __restrict__ amin) {
  const int g = blockIdx.x, b = blockIdx.y, lane = threadIdx.x;
  const float* Cr = cost + ((size_t)b * GG + g) * STRIDE + lane;
  double m1 = 1e301, m2 = 1e301;
  int i1 = 0x3FFFFFFF;
#pragma unroll
  for (int k = 0; k < KPL; ++k) {
    const double c = (double)Cr[64 * k];
    const int j = 1 + lane + 64 * k;
    if (c < m1) { m2 = m1; m1 = c; i1 = j; }
    else if (c < m2) m2 = c;
  }
  for (int m = 1; m < 64; m <<= 1) {
    const double o1 = __shfl_xor(m1, m), o2 = __shfl_xor(m2, m);
    const int oi = __shfl_xor(i1, m);
    if (o1 < m1 || (o1 == m1 && oi < i1)) { m2 = (m1 < o2 ? m1 : o2); m1 = o1; i1 = oi; }
    else { m2 = (o1 < m2 ? o1 : m2); }
  }
  if (lane == 0) { mins[b * GG + g] = make_float2((float)m1, (float)m2); amin[b * GG + g] = i1; }
}

// ---------------- JV: parallel greedy + ARR + (fallback) Dijkstra + fused loss ----------------
__global__ __launch_bounds__(64) void jv_kernel(
    const float* __restrict__ logits, const float* __restrict__ pboxes,
    const int* __restrict__ gcls, const float* __restrict__ gboxes,
    const float* __restrict__ cost, const float2* __restrict__ mins,
    const int* __restrict__ amin, Accum* acc, float* out) {
  const int b = blockIdx.x;
  const int lane = threadIdx.x;

  __shared__ double u[GG + 2];
  __shared__ double vl[STRIDE + 2];
  __shared__ int p[QQ + 1];
  __shared__ int way[STRIDE + 2];      // claim scratch during greedy round, parent in Dijkstra
  __shared__ int tree_rows[GG + 2];
  __shared__ int queue[QSIZE];
  __shared__ int sh_n, sh_qtail;

  {
    int c = 0;
    for (int g = lane; g < GG; g += 64) c += (gcls[b * GG + g] >= 0) ? 1 : 0;
    for (int off = 32; off; off >>= 1) c += __shfl_down(c, off);
    if (lane == 0) { sh_n = c; sh_qtail = 0; }
  }
  for (int j = lane; j <= QQ; j += 64) p[j] = 0;
  for (int j = lane; j <= STRIDE + 1; j += 64) { vl[j] = 0.0; way[j] = 0x7FFFFFFF; }
  for (int r = lane; r <= GG + 1; r += 64) u[r] = 0.0;
  __syncthreads();

  const int n = sh_n;
  const float* Cb = cost + (size_t)b * GG * STRIDE;

  // ---- parallel greedy round (valid ARR steps: v == 0 at proposal time) ----
  for (int r = lane; r < n; r += 64) atomicMin(&way[amin[b * GG + r]], r);
  __syncthreads();
  for (int r = lane; r < n; r += 64) {
    const int j1 = amin[b * GG + r];
    const float2 mm = mins[b * GG + r];
    if (way[j1] == r) {  // winner: claim j1, CS holds with u=min2, v=min1-min2
      p[j1] = r + 1; u[r + 1] = (double)mm.y; vl[j1] = (double)mm.x - (double)mm.y;
    } else {             // loser: u=min1 is dual-feasible forever (v only decreases)
      u[r + 1] = (double)mm.x;
      const int t = atomicAdd(&sh_qtail, 1);
      queue[t] = r + 1;
    }
  }
  __syncthreads();

  // ---- ARR rescan queue: one wave-parallel scan per iteration ----
  float rc[KPL];
  int head = 0, iter = 0, pf = -1;
  while (true) {
    const int qt = sh_qtail;
    if (head >= qt || iter >= ARR_CAP) break;
    const int i = queue[head]; head++;
    if (pf != i) {  // prefetch miss (first iter / just-bumped row)
      const float* Cr = Cb + (size_t)(i - 1) * STRIDE + lane;
#pragma unroll
      for (int k = 0; k < KPL; ++k) rc[k] = Cr[64 * k];
    }
    double m1 = 1e301, m2 = 1e301;
    int j1 = 0x3FFFFFFF;
#pragma unroll
    for (int k = 0; k < KPL; ++k) {
      const double c = (double)rc[k] - vl[1 + lane + 64 * k];
      const int j = 1 + lane + 64 * k;
      if (c < m1) { m2 = m1; m1 = c; j1 = j; }
      else if (c < m2) m2 = c;
    }
    for (int m = 1; m < 64; m <<= 1) {
      const double o1 = __shfl_xor(m1, m), o2 = __shfl_xor(m2, m);
      const int oi = __shfl_xor(j1, m);
      if (o1 < m1 || (o1 == m1 && oi < j1)) { m2 = (m1 < o2 ? m1 : o2); m1 = o1; j1 = oi; }
      else { m2 = (o1 < m2 ? o1 : m2); }
    }
    if (lane == 0) {
      u[i] = m2;
      vl[j1] -= (m2 - m1);
      const int k0 = p[j1]; p[j1] = i;
      if (k0) { queue[sh_qtail] = k0; sh_qtail = sh_qtail + 1; }
    }
    __syncthreads();   // publish vl/p/queue/qtail
    pf = -1;
    if (head < sh_qtail) {  // pop order is FIFO: prefetch is always exact
      pf = queue[head];
      const float* Cr = Cb + (size_t)(pf - 1) * STRIDE + lane;
#pragma unroll
      for (int k = 0; k < KPL; ++k) rc[k] = Cr[64 * k];
    }
    iter++;
    __syncthreads();
  }

  // ---- exact Dijkstra fallback for cap leftovers (expected: none) ----
  __syncthreads();
  const int qtf = sh_qtail;
  if (head < qtf) {
    double vd[KPL], minv[KPL];
#pragma unroll
    for (int k = 0; k < KPL; ++k) vd[k] = vl[1 + lane + 64 * k];
    for (int ii = head; ii < qtf; ++ii) {
      const int i = queue[ii];
#pragma unroll
      for (int k = 0; k < KPL; ++k) minv[k] = 1e300;
      unsigned int usedm = 0;
      int j0 = 0, i0 = i, t = 0;
      if (lane == 0) p[0] = i;
      double ui0 = u[i];
      {
        const float* Cr = Cb + (size_t)(i - 1) * STRIDE + lane;
#pragma unroll
        for (int k = 0; k < KPL; ++k) rc[k] = Cr[64 * k];
      }
      int j1;
      while (true) {
        if (j0 > 0) { const int c = j0 - 1; if ((c & 63) == lane) usedm |= 1u << (c >> 6); }
        if (lane == 0) tree_rows[t] = i0;
        t++;
        double lval = 1e301; int lidx = 0x3FFFFFFF;
#pragma unroll
        for (int k = 0; k < KPL; ++k) {
          const bool us = (usedm >> k) & 1u;
          const double cur = (double)rc[k] - ui0 - vd[k];
          if (!us && cur < minv[k]) { minv[k] = cur; way[1 + lane + 64 * k] = j0; }
          const double mv = us ? 1e301 : minv[k];
          if (mv < lval) { lval = mv; lidx = 1 + lane + 64 * k; }
        }
        for (int m = 1; m < 64; m <<= 1) {
          const double ov = __shfl_xor(lval, m);
          const int oi = __shfl_xor(lidx, m);
          if (ov < lval || (ov == lval && oi < lidx)) { lval = ov; lidx = oi; }
        }
        const double delta = lval;
        j1 = lidx;
        __syncthreads();
        for (int s = lane; s < t; s += 64) u[tree_rows[s]] += delta;
#pragma unroll
        for (int k = 0; k < KPL; ++k) {
          if ((usedm >> k) & 1u) vd[k] -= delta; else minv[k] -= delta;
        }
        const int i0n = p[j1];
        if (i0n == 0) break;
        ui0 = u[i0n];
        {
          const float* Cr = Cb + (size_t)(i0n - 1) * STRIDE + lane;
#pragma unroll
          for (int k = 0; k < KPL; ++k) rc[k] = Cr[64 * k];
        }
        j0 = j1; i0 = i0n;
      }
      if (lane == 0) {
        int jj = j1;
        while (jj) { const int jn = way[jj]; p[jj] = p[jn]; jj = jn; }
      }
      __syncthreads();
    }
  }
  __syncthreads();

  // ---- fused loss over this batch's 900 queries ----
  double wnll = 0.0, wt = 0.0, l1d = 0.0, gld = 0.0;
  int nm = 0;
  for (int q = lane; q < QQ; q += 64) {
    const int idx = b * QQ + q;
    const float* lg = logits + (size_t)idx * CP1;
    float l[CP1];
    float mx = -1e30f;
    for (int c = 0; c < CP1; ++c) { l[c] = lg[c]; mx = fmaxf(mx, l[c]); }
    float se = 0.f;
    for (int c = 0; c < CP1; ++c) se += expf(l[c] - mx);
    const float lse = logf(se);
    const int g = p[q + 1] - 1;   // row -> gt index (valid gts are a prefix)
    const int t = (g >= 0) ? gcls[b * GG + g] : NCLS;
    float lt = l[0];
    for (int c = 1; c < CP1; ++c) lt = (c == t) ? l[c] : lt;
    const float logp = (lt - mx) - lse;
    const float w = (t == NCLS) ? 0.1f : 1.0f;
    wnll += (double)(w * (-logp));
    wt += (double)w;
    if (g >= 0) {
      nm += 1;
      const float* pb = pboxes + (size_t)idx * 4;
      const float* gb = gboxes + ((size_t)b * GG + g) * 4;
      const float pcx = pb[0], pcy = pb[1], pw = pb[2], ph = pb[3];
      const float gcx = gb[0], gcy = gb[1], gw = gb[2], gh = gb[3];
      const float l1 = fabsf(pcx - gcx) + fabsf(pcy - gcy) + fabsf(pw - gw) + fabsf(ph - gh);
      const float px1 = pcx - 0.5f * pw, py1 = pcy - 0.5f * ph;
      const float px2 = pcx + 0.5f * pw, py2 = pcy + 0.5f * ph;
      const float gx1 = gcx - 0.5f * gw, gy1 = gcy - 0.5f * gh;
      const float gx2 = gcx + 0.5f * gw, gy2 = gcy + 0.5f * gh;
      const float pa = fmaxf(px2 - px1, 0.f) * fmaxf(py2 - py1, 0.f);
      const float ga = fmaxf(gx2 - gx1, 0.f) * fmaxf(gy2 - gy1, 0.f);
      const float ltx = fmaxf(px1, gx1), lty = fmaxf(py1, gy1);
      const float rbx = fminf(px2, gx2), rby = fminf(py2, gy2);
      const float iw = fmaxf(rbx - ltx, 0.f), ih = fmaxf(rby - lty, 0.f);
      const float inter = iw * ih;
      const float uni = pa + ga - inter;
      const float iou = inter / fmaxf(uni, 1e-6f);
      const float ex1 = fminf(px1, gx1), ey1 = fminf(py1, gy1);
      const float ex2 = fmaxf(px2, gx2), ey2 = fmaxf(py2, gy2);
      const float ew = fmaxf(ex2 - ex1, 0.f), eh = fmaxf(ey2 - ey1, 0.f);
      const float enc = ew * eh;
      const float giou = iou - (enc - uni) / fmaxf(enc, 1e-6f);
      l1d += (double)l1;
      gld += (double)(1.0f - giou);
    }
  }

  for (int off = 32; off; off >>= 1) {
    wnll += __shfl_down(wnll, off);
    wt   += __shfl_down(wt, off);
    l1d  += __shfl_down(l1d, off);
    gld  += __shfl_down(gld, off);
    nm   += __shfl_down(nm, off);
  }
  if (lane == 0) {
    atomicAdd(&acc->wnll, wnll);
    atomicAdd(&acc->wt, wt);
    atomicAdd(&acc->l1, l1d);
    atomicAdd(&acc->gl, gld);
    atomicAdd(&acc->nm, nm);
    __threadfence();
    const int ticket = atomicAdd(&acc->counter, 1);
    if (ticket == BB - 1) {
      const double fw = atomicAdd(&acc->wnll, 0.0);
      const double fwt = atomicAdd(&acc->wt, 0.0);
      const double fl1 = atomicAdd(&acc->l1, 0.0);
      const double fgl = atomicAdd(&acc->gl, 0.0);
      int fnm = atomicAdd(&acc->nm, 0);
      if (fnm < 1) fnm = 1;
      const double loss = (double)CLS_W * (fw / fwt) +
                          ((double)L1_W * fl1 + (double)GIOU_W * fgl) / (double)fnm;
      out[0] = (float)loss;
    }
  }
}

extern "C" void kernel_launch(void* const* d_in, const int* in_sizes, int n_in,
                              void* d_out, int out_size, void* d_ws, size_t ws_size,
                              hipStream_t stream) {
  const float* logits = (const float*)d_in[0];
  const float* pboxes = (const float*)d_in[1];
  const int*   gcls   = (const int*)d_in[2];
  const float* gboxes = (const float*)d_in[3];

  char* ws = (char*)d_ws;
  Accum* acc = (Accum*)ws;                                        // 64 B
  float2* mins = (float2*)(ws + 128);                             // B*G float2 = 51.2 KB
  int* amin = (int*)(ws + 128 + (size_t)BB * GG * 8);             // B*G ints = 25.6 KB
  float* cost = (float*)(ws + 128 + (size_t)BB * GG * 12 + 64);   // B*G*960 floats ~ 24.6 MB

  cost_kernel<<<dim3((STRIDE + 255) / 256, BB), 256, 0, stream>>>(logits, pboxes, gcls, gboxes, cost, acc);
  rowmin_kernel<<<dim3(GG, BB), 64, 0, stream>>>(cost, mins, amin);
  jv_kernel<<<BB, 64, 0, stream>>>(logits, pboxes, gcls, gboxes, cost, mins, amin, acc, (float*)d_out);
}

// Round 5
// 124.686 us; speedup vs baseline: 3.5707x; 1.1740x over previous
//
#include <hip/hip_runtime.h>
#include <hip/hip_bf16.h>
#include <math.h>

#define BB 64
#define QQ 900
#define GG 100
#define NCLS 10
#define CP1 11

#define STRIDE 960   // 64*15: every lane owns exactly KPL columns; cols 900..959 are +inf pads
#define KPL 15
#define NW 8         // waves per jv block
#define NT 512
#define QMASK 255    // ring queue; live entries <= n <= 100 < 256
#define ROUND_CAP 2000

#define CLS_W 2.0f
#define L1_W 5.0f
#define GIOU_W 2.0f

struct Accum {
  double wnll, wt, l1, gl;
  int nm, counter;
  int pad[6];
};

// ---------------- cost matrix: cost[b][g][q], row stride 960 (pads = 1e30) ----------------
__global__ __launch_bounds__(256) void cost_kernel(
    const float* __restrict__ logits, const float* __restrict__ pboxes,
    const int* __restrict__ gcls, const float* __restrict__ gboxes,
    float* __restrict__ cost, Accum* acc) {
  const int b = blockIdx.y;
  const int q = blockIdx.x * 256 + threadIdx.x;

  if (blockIdx.x == 0 && blockIdx.y == 0 && threadIdx.x == 0) {
    acc->wnll = 0.0; acc->wt = 0.0; acc->l1 = 0.0; acc->gl = 0.0;
    acc->nm = 0; acc->counter = 0;
  }

  __shared__ float s_gb[GG * 4];
  __shared__ int   s_gc[GG];
  __shared__ float s_prob[256 * 13];

  for (int i = threadIdx.x; i < GG * 4; i += 256) s_gb[i] = gboxes[b * GG * 4 + i];
  for (int i = threadIdx.x; i < GG; i += 256)     s_gc[i] = gcls[b * GG + i];

  float pcx = 0.f, pcy = 0.f, pw = 0.f, ph = 0.f;
  if (q < QQ) {
    const float* lg = logits + ((size_t)b * QQ + q) * CP1;
    float l[CP1];
    float mx = -1e30f;
    for (int c = 0; c < CP1; ++c) { l[c] = lg[c]; mx = fmaxf(mx, l[c]); }
    float se = 0.f;
    for (int c = 0; c < CP1; ++c) { l[c] = expf(l[c] - mx); se += l[c]; }
    float inv = 1.0f / se;
    for (int c = 0; c < CP1; ++c) s_prob[threadIdx.x * 13 + c] = l[c] * inv;
    const float* pb = pboxes + ((size_t)b * QQ + q) * 4;
    pcx = pb[0]; pcy = pb[1]; pw = pb[2]; ph = pb[3];
  }
  __syncthreads();
  if (q >= STRIDE) return;

  float* crow = cost + ((size_t)b * GG) * STRIDE + q;
  if (q >= QQ) {  // pad columns: huge cost, never selected
    for (int g = 0; g < GG; ++g) crow[(size_t)g * STRIDE] = 1e30f;
    return;
  }

  const float px1 = pcx - 0.5f * pw, py1 = pcy - 0.5f * ph;
  const float px2 = pcx + 0.5f * pw, py2 = pcy + 0.5f * ph;
  const float pa = fmaxf(px2 - px1, 0.f) * fmaxf(py2 - py1, 0.f);

  for (int g = 0; g < GG; ++g) {
    int cls = s_gc[g];
    cls = cls < 0 ? 0 : (cls > NCLS - 1 ? NCLS - 1 : cls);
    const float cc = -s_prob[threadIdx.x * 13 + cls];
    const float gcx = s_gb[g * 4 + 0], gcy = s_gb[g * 4 + 1];
    const float gw  = s_gb[g * 4 + 2], gh  = s_gb[g * 4 + 3];
    const float l1 = fabsf(pcx - gcx) + fabsf(pcy - gcy) + fabsf(pw - gw) + fabsf(ph - gh);
    const float gx1 = gcx - 0.5f * gw, gy1 = gcy - 0.5f * gh;
    const float gx2 = gcx + 0.5f * gw, gy2 = gcy + 0.5f * gh;
    const float ga = fmaxf(gx2 - gx1, 0.f) * fmaxf(gy2 - gy1, 0.f);
    const float ltx = fmaxf(px1, gx1), lty = fmaxf(py1, gy1);
    const float rbx = fminf(px2, gx2), rby = fminf(py2, gy2);
    const float iw = fmaxf(rbx - ltx, 0.f), ih = fmaxf(rby - lty, 0.f);
    const float inter = iw * ih;
    const float uni = pa + ga - inter;
    const float iou = inter / fmaxf(uni, 1e-6f);
    const float ex1 = fminf(px1, gx1), ey1 = fminf(py1, gy1);
    const float ex2 = fmaxf(px2, gx2), ey2 = fmaxf(py2, gy2);
    const float ew = fmaxf(ex2 - ex1, 0.f), eh = fmaxf(ey2 - ey1, 0.f);
    const float enc = ew * eh;
    const float giou = iou - (enc - uni) / fmaxf(enc, 1e-6f);
    crow[(size_t)g * STRIDE] = CLS_W * cc + L1_W * l1 - GIOU_W * giou;
  }
}

// ---------------- JV: fused rowmin + greedy + Jacobi-parallel ARR + Dijkstra fallback + loss ----
__global__ __launch_bounds__(NT) void jv_kernel(
    const float* __restrict__ logits, const float* __restrict__ pboxes,
    const int* __restrict__ gcls, const float* __restrict__ gboxes,
    const float* __restrict__ cost, Accum* acc, float* out) {
  const int b = blockIdx.x;
  const int tid = threadIdx.x;
  const int lane = tid & 63;
  const int w = tid >> 6;

  __shared__ double u[GG + 2];
  __shared__ double vl[STRIDE + 2];
  __shared__ double m1l[GG + 1], m2l[GG + 1];
  __shared__ int aminl[GG + 1];
  __shared__ int p[QQ + 1];
  __shared__ int way[STRIDE + 2];      // claim scratch in greedy, parent in Dijkstra
  __shared__ int tree_rows[GG + 2];
  __shared__ int queue[QMASK + 1];
  __shared__ int prop_j[NW], prop_i[NW];
  __shared__ double prop_m1[NW], prop_m2[NW];
  __shared__ int sh_n, sh_qhead, sh_qtail;
  __shared__ double sh_delta;
  __shared__ int sh_j1, sh_i0n;
  __shared__ double r0[NW], r1[NW], r2[NW], r3[NW];
  __shared__ int r4[NW];

  if (tid == 0) { sh_n = 0; sh_qhead = 0; sh_qtail = 0; }
  for (int j = tid; j <= QQ; j += NT) p[j] = 0;
  for (int j = tid; j <= STRIDE + 1; j += NT) { vl[j] = 0.0; way[j] = 0x7FFFFFFF; }
  __syncthreads();
  if (tid < GG && gcls[b * GG + tid] >= 0) atomicAdd(&sh_n, 1);
  __syncthreads();
  const int n = sh_n;
  const float* Cb = cost + (size_t)b * GG * STRIDE;

  // ---- Phase 1: per-row (min1, min2, argmin), 8 waves in parallel ----
  for (int r = w; r < n; r += NW) {
    const float* Cr = Cb + (size_t)r * STRIDE + lane;
    float rca[KPL];
#pragma unroll
    for (int k = 0; k < KPL; ++k) rca[k] = Cr[64 * k];
    double m1 = 1e301, m2 = 1e301;
    int j1 = 0x3FFFFFFF;
#pragma unroll
    for (int k = 0; k < KPL; ++k) {
      const double c = (double)rca[k];
      const int j = 1 + lane + 64 * k;
      if (c < m1) { m2 = m1; m1 = c; j1 = j; }
      else if (c < m2) m2 = c;
    }
    for (int m = 1; m < 64; m <<= 1) {
      const double o1 = __shfl_xor(m1, m), o2 = __shfl_xor(m2, m);
      const int oi = __shfl_xor(j1, m);
      if (o1 < m1 || (o1 == m1 && oi < j1)) { m2 = (m1 < o2 ? m1 : o2); m1 = o1; j1 = oi; }
      else { m2 = (o1 < m2 ? o1 : m2); }
    }
    if (lane == 0) { m1l[r] = m1; m2l[r] = m2; aminl[r] = j1; }
  }
  __syncthreads();

  // ---- Phase 2: parallel greedy claim (valid ARR steps at v == 0) ----
  if (tid < n) atomicMin(&way[aminl[tid]], tid);
  __syncthreads();
  if (tid < n) {
    const int j1 = aminl[tid];
    if (way[j1] == tid) {   // winner: u=min2, v=min1-min2, CS equality at (tid+1, j1)
      p[j1] = tid + 1; u[tid + 1] = m2l[tid]; vl[j1] = m1l[tid] - m2l[tid];
    } else {                // loser: u=min1 stays feasible (v only decreases)
      u[tid + 1] = m1l[tid];
      const int t0 = atomicAdd(&sh_qtail, 1);
      queue[t0 & QMASK] = tid + 1;
    }
  }
  __syncthreads();

  // ---- Phase 3: Jacobi-parallel ARR rounds (8 rows scanned per round, exact) ----
  float rc[KPL];
  int my_i = -1;
  {
    const int h = sh_qhead, t = sh_qtail;
    if (h + w < t) {
      my_i = queue[(h + w) & QMASK];
      const float* Cr = Cb + (size_t)(my_i - 1) * STRIDE + lane;
#pragma unroll
      for (int k = 0; k < KPL; ++k) rc[k] = Cr[64 * k];
    }
  }
  int rounds = 0;
  while (true) {
    __syncthreads();
    const int h = sh_qhead, t = sh_qtail;
    const int act = (t - h) < NW ? (t - h) : NW;
    if (act <= 0 || rounds >= ROUND_CAP) break;

    if (w < act) {   // invariant: my_i valid, rc holds its row
      double m1 = 1e301, m2 = 1e301;
      int j1 = 0x3FFFFFFF;
#pragma unroll
      for (int k = 0; k < KPL; ++k) {
        const double c = (double)rc[k] - vl[1 + lane + 64 * k];
        const int j = 1 + lane + 64 * k;
        if (c < m1) { m2 = m1; m1 = c; j1 = j; }
        else if (c < m2) m2 = c;
      }
      for (int m = 1; m < 64; m <<= 1) {
        const double o1 = __shfl_xor(m1, m), o2 = __shfl_xor(m2, m);
        const int oi = __shfl_xor(j1, m);
        if (o1 < m1 || (o1 == m1 && oi < j1)) { m2 = (m1 < o2 ? m1 : o2); m1 = o1; j1 = oi; }
        else { m2 = (o1 < m2 ? o1 : m2); }
      }
      if (lane == 0) { prop_j[w] = j1; prop_i[w] = my_i; prop_m1[w] = m1; prop_m2[w] = m2; }
    }
    // speculative prefetch of next round's row (pops below old tail are stable)
    const int nh = h + act;
    int spec = -1;
    if (nh + w < t) {
      spec = queue[(nh + w) & QMASK];
      const float* Cr = Cb + (size_t)(spec - 1) * STRIDE + lane;
#pragma unroll
      for (int k = 0; k < KPL; ++k) rc[k] = Cr[64 * k];
    }
    __syncthreads();

    if (tid == 0) {   // arbitration in queue order; at most one winner per column
      int qt = sh_qtail;
      bool won[NW];
      for (int x = 0; x < act; ++x) {
        const int j = prop_j[x], i = prop_i[x];
        bool lost = false;
        for (int y = 0; y < x; ++y) if (won[y] && prop_j[y] == j) { lost = true; break; }
        won[x] = !lost;
        if (lost) { queue[qt & QMASK] = i; qt++; }
        else {
          u[i] = prop_m2[x];
          vl[j] -= prop_m2[x] - prop_m1[x];
          const int k0 = p[j]; p[j] = i;
          if (k0) { queue[qt & QMASK] = k0; qt++; }
        }
      }
      sh_qhead = nh; sh_qtail = qt;
    }
    __syncthreads();

    if (spec >= 1) my_i = spec;
    else {
      const int h2 = sh_qhead, t2 = sh_qtail;
      if (h2 + w < t2) {
        my_i = queue[(h2 + w) & QMASK];
        const float* Cr = Cb + (size_t)(my_i - 1) * STRIDE + lane;
#pragma unroll
        for (int k = 0; k < KPL; ++k) rc[k] = Cr[64 * k];
      } else my_i = -1;
    }
    rounds++;
  }

  // ---- Phase 4: exact Dijkstra fallback for ROUND_CAP leftovers (expected: never) ----
  __syncthreads();
  {
    const int headf = sh_qhead, qtf = sh_qtail;
    if (headf < qtf) {
      double vd[KPL], minv[KPL];
      float rcd[KPL];
      unsigned int usedm = 0;
      int j0 = 0, i0 = 0, tt = 0;
      double ui0 = 0.0;
      if (tid < 64) {
#pragma unroll
        for (int k = 0; k < KPL; ++k) vd[k] = vl[1 + lane + 64 * k];
      }
      for (int ii = headf; ii < qtf; ++ii) {
        const int i = queue[ii & QMASK];
        if (tid < 64) {
#pragma unroll
          for (int k = 0; k < KPL; ++k) minv[k] = 1e300;
          usedm = 0; j0 = 0; i0 = i; tt = 0;
          ui0 = u[i];
          const float* Cr = Cb + (size_t)(i - 1) * STRIDE + lane;
#pragma unroll
          for (int k = 0; k < KPL; ++k) rcd[k] = Cr[64 * k];
        }
        if (tid == 0) p[0] = i;
        __syncthreads();
        int j1 = 0;
        while (true) {
          if (tid < 64) {
            if (j0 > 0) { const int c = j0 - 1; if ((c & 63) == lane) usedm |= 1u << (c >> 6); }
            if (tid == 0) tree_rows[tt] = i0;
            tt++;
            double lval = 1e301; int lidx = 0x3FFFFFFF;
#pragma unroll
            for (int k = 0; k < KPL; ++k) {
              const bool us = (usedm >> k) & 1u;
              const double cur = (double)rcd[k] - ui0 - vd[k];
              if (!us && cur < minv[k]) { minv[k] = cur; way[1 + lane + 64 * k] = j0; }
              const double mv = us ? 1e301 : minv[k];
              if (mv < lval) { lval = mv; lidx = 1 + lane + 64 * k; }
            }
            for (int m = 1; m < 64; m <<= 1) {
              const double ov = __shfl_xor(lval, m);
              const int oi = __shfl_xor(lidx, m);
              if (ov < lval || (ov == lval && oi < lidx)) { lval = ov; lidx = oi; }
            }
            if (tid == 0) { sh_delta = lval; sh_j1 = lidx; }
          }
          __syncthreads();
          const double delta = sh_delta;
          j1 = sh_j1;
          if (tid < 64) {
            for (int s = lane; s < tt; s += 64) u[tree_rows[s]] += delta;
#pragma unroll
            for (int k = 0; k < KPL; ++k) {
              if ((usedm >> k) & 1u) vd[k] -= delta; else minv[k] -= delta;
            }
          }
          if (tid == 0) sh_i0n = p[j1];
          __syncthreads();
          const int i0n = sh_i0n;
          if (i0n == 0) break;
          if (tid < 64) {
            ui0 = u[i0n];
            const float* Cr = Cb + (size_t)(i0n - 1) * STRIDE + lane;
#pragma unroll
            for (int k = 0; k < KPL; ++k) rcd[k] = Cr[64 * k];
            j0 = j1; i0 = i0n;
          }
        }
        if (tid == 0) {
          int jj = j1;
          while (jj) { const int jn = way[jj]; p[jj] = p[jn]; jj = jn; }
        }
        __syncthreads();
      }
    }
  }
  __syncthreads();

  // ---- Phase 5: fused loss over this batch's 900 queries (512 threads) ----
  double wnll = 0.0, wt = 0.0, l1d = 0.0, gld = 0.0;
  int nm = 0;
  for (int q = tid; q < QQ; q += NT) {
    const int idx = b * QQ + q;
    const float* lg = logits + (size_t)idx * CP1;
    float l[CP1];
    float mx = -1e30f;
    for (int c = 0; c < CP1; ++c) { l[c] = lg[c]; mx = fmaxf(mx, l[c]); }
    float se = 0.f;
    for (int c = 0; c < CP1; ++c) se += expf(l[c] - mx);
    const float lse = logf(se);
    const int g = p[q + 1] - 1;   // row -> gt index (valid gts are a prefix)
    const int t = (g >= 0) ? gcls[b * GG + g] : NCLS;
    float lt = l[0];
    for (int c = 1; c < CP1; ++c) lt = (c == t) ? l[c] : lt;
    const float logp = (lt - mx) - lse;
    const float wgt = (t == NCLS) ? 0.1f : 1.0f;
    wnll += (double)(wgt * (-logp));
    wt += (double)wgt;
    if (g >= 0) {
      nm += 1;
      const float* pb = pboxes + (size_t)idx * 4;
      const float* gb = gboxes + ((size_t)b * GG + g) * 4;
      const float pcx = pb[0], pcy = pb[1], pw = pb[2], ph = pb[3];
      const float gcx = gb[0], gcy = gb[1], gw = gb[2], gh = gb[3];
      const float l1 = fabsf(pcx - gcx) + fabsf(pcy - gcy) + fabsf(pw - gw) + fabsf(ph - gh);
      const float px1 = pcx - 0.5f * pw, py1 = pcy - 0.5f * ph;
      const float px2 = pcx + 0.5f * pw, py2 = pcy + 0.5f * ph;
      const float gx1 = gcx - 0.5f * gw, gy1 = gcy - 0.5f * gh;
      const float gx2 = gcx + 0.5f * gw, gy2 = gcy + 0.5f * gh;
      const float pa = fmaxf(px2 - px1, 0.f) * fmaxf(py2 - py1, 0.f);
      const float ga = fmaxf(gx2 - gx1, 0.f) * fmaxf(gy2 - gy1, 0.f);
      const float ltx = fmaxf(px1, gx1), lty = fmaxf(py1, gy1);
      const float rbx = fminf(px2, gx2), rby = fminf(py2, gy2);
      const float iw = fmaxf(rbx - ltx, 0.f), ih = fmaxf(rby - lty, 0.f);
      const float inter = iw * ih;
      const float uni = pa + ga - inter;
      const float iou = inter / fmaxf(uni, 1e-6f);
      const float ex1 = fminf(px1, gx1), ey1 = fminf(py1, gy1);
      const float ex2 = fmaxf(px2, gx2), ey2 = fmaxf(py2, gy2);
      const float ew = fmaxf(ex2 - ex1, 0.f), eh = fmaxf(ey2 - ey1, 0.f);
      const float enc = ew * eh;
      const float giou = iou - (enc - uni) / fmaxf(enc, 1e-6f);
      l1d += (double)l1;
      gld += (double)(1.0f - giou);
    }
  }

  for (int off = 32; off; off >>= 1) {
    wnll += __shfl_down(wnll, off);
    wt   += __shfl_down(wt, off);
    l1d  += __shfl_down(l1d, off);
    gld  += __shfl_down(gld, off);
    nm   += __shfl_down(nm, off);
  }
  if (lane == 0) { r0[w] = wnll; r1[w] = wt; r2[w] = l1d; r3[w] = gld; r4[w] = nm; }
  __syncthreads();
  if (tid == 0) {
    for (int x = 1; x < NW; ++x) { wnll += r0[x]; wt += r1[x]; l1d += r2[x]; gld += r3[x]; nm += r4[x]; }
    atomicAdd(&acc->wnll, wnll);
    atomicAdd(&acc->wt, wt);
    atomicAdd(&acc->l1, l1d);
    atomicAdd(&acc->gl, gld);
    atomicAdd(&acc->nm, nm);
    __threadfence();
    const int ticket = atomicAdd(&acc->counter, 1);
    if (ticket == BB - 1) {
      const double fw = atomicAdd(&acc->wnll, 0.0);
      const double fwt = atomicAdd(&acc->wt, 0.0);
      const double fl1 = atomicAdd(&acc->l1, 0.0);
      const double fgl = atomicAdd(&acc->gl, 0.0);
      int fnm = atomicAdd(&acc->nm, 0);
      if (fnm < 1) fnm = 1;
      const double loss = (double)CLS_W * (fw / fwt) +
                          ((double)L1_W * fl1 + (double)GIOU_W * fgl) / (double)fnm;
      out[0] = (float)loss;
    }
  }
}

extern "C" void kernel_launch(void* const* d_in, const int* in_sizes, int n_in,
                              void* d_out, int out_size, void* d_ws, size_t ws_size,
                              hipStream_t stream) {
  const float* logits = (const float*)d_in[0];
  const float* pboxes = (const float*)d_in[1];
  const int*   gcls   = (const int*)d_in[2];
  const float* gboxes = (const float*)d_in[3];

  char* ws = (char*)d_ws;
  Accum* acc = (Accum*)ws;                 // 64 B
  float* cost = (float*)(ws + 128);        // B*G*960 floats ~ 24.6 MB

  cost_kernel<<<dim3((STRIDE + 255) / 256, BB), 256, 0, stream>>>(logits, pboxes, gcls, gboxes, cost, acc);
  jv_kernel<<<BB, NT, 0, stream>>>(logits, pboxes, gcls, gboxes, cost, acc, (float*)d_out);
}